// Round 10
// baseline (146.611 us; speedup 1.0000x reference)
//
#include <hip/hip_runtime.h>
#include <math.h>

// MMD loss. Z = concat(X,Y) [8192 x 256] fp32.
// Round 18: R17's VGPR=124 reveals the compiler collapsed the 4-set pipeline
//   to just-in-time loads -- and STILL matched R13 (49.5 vs 48.5us). Re-based
//   model with per-SIMD MFMA rate (~19cyc per 16x16x32, 844 FLOP/cyc/SIMD):
//   pipe demands are only ~35-40K cyc/SIMD (MfmaUtil/VALUBusy agree) vs 120K
//   wall. Binding constraint all session: 2 waves/SIMD of latency cover.
//   R17's structure (no LDS, no barriers, 124 VGPR) makes 4 blocks/CU legal;
//   only the 512-grid prevented it. One lever: grid 1040 x 2 tiles
//   (2080 exact, 8*130 XCD-clean), __launch_bounds__(256,4), plain per-slice
//   load+MFMA loop (what the compiler emits anyway). 4 independent load
//   streams/SIMD cover each other's ~300cyc L2 stalls.
//   Canary: WRITE_SIZE ~34KB (MB-scale => 4-wave VGPR budget failed).
// Math (R5-R17 verified, absmax 0.0): 1-phase bf16 Gram, sq exact fp32;
//   d2 = sq_i + sq_j - 2 z_i.z_j; bandwidth analytic
//   (sum d2 = 2M*S - 2||sum z||^2); K = t+t^2+t^4+t^8+t^16, t=exp(-d2/(4bw));
//   out = (Sxx + Syy - Sxy_both)/n^2, fp64 accumulation.

#define N_HALF 4096
#define DIM 256
#define M_TOT 8192
#define TILE 128
#define NT 64
#define NT_HALF 32
#define NCHUNK 1040  // blocks x 2 tiles = 2080 flat-triangle tiles exactly

typedef unsigned short ushort_t;
typedef __attribute__((ext_vector_type(8))) short short8;   // 8 bf16 = 4 VGPRs
typedef __attribute__((ext_vector_type(4))) float floatx4;  // MFMA C/D

// Fragment-swizzled bf16 Z (4 MB). For row-block rb (16 rows) and k-chunk kk
// (32 k): g_zf[rb*4096 + kk*512 + q*128 + m*8 + j] = Z[rb*16+m][kk*32+q*8+j].
// The 16B unit of lane (quad=q, l15=m) sits at byte lane*16 within the 1KB
// chunk: frag global_load_dwordx4 is linear in lane -> fully coalesced 1KB.
__device__ ushort_t g_zf[M_TOT * DIM];

__device__ __forceinline__ ushort_t f2bf(float f) {  // RNE, finite inputs
    unsigned u = __float_as_uint(f);
    u += 0x7fffu + ((u >> 16) & 1u);
    return (ushort_t)(u >> 16);
}

// ---------------- k_prep: convert(swizzled) + row norms + col sums -----------
// 512 blocks x 256 threads; wave w owns 4 rows; lane l owns cols [4l,4l+4).
__global__ __launch_bounds__(256) void k_prep(const float* __restrict__ X,
                                              const float* __restrict__ Y,
                                              float* __restrict__ sq,
                                              float* __restrict__ colsum_r,
                                              float* __restrict__ Ssum_r) {
    __shared__ float cpart[4][256];
    __shared__ float spart[4];
    const int t = threadIdx.x, wave = t >> 6, lane = t & 63;
    const int row0 = blockIdx.x * 16 + wave * 4;
    // swizzle coords for this lane's 4 columns [4l, 4l+4)
    const int kk = lane >> 3, q = (lane >> 1) & 3, j0 = (lane & 1) * 4;
    float c0 = 0.f, c1 = 0.f, c2 = 0.f, c3 = 0.f, ssum = 0.f;
#pragma unroll
    for (int i = 0; i < 4; ++i) {
        const int row = row0 + i;
        const float* p = (row < N_HALF) ? (X + (size_t)row * DIM)
                                        : (Y + (size_t)(row - N_HALF) * DIM);
        const float4 v = *((const float4*)p + lane);
        ushort4 hi;
        hi.x = f2bf(v.x); hi.y = f2bf(v.y); hi.z = f2bf(v.z); hi.w = f2bf(v.w);
        const int rb = row >> 4, m = row & 15;
        *(ushort4*)(g_zf + (size_t)rb * 4096 + kk * 512 + q * 128 + m * 8 + j0) = hi;
        c0 += v.x; c1 += v.y; c2 += v.z; c3 += v.w;
        float s = fmaf(v.x, v.x, fmaf(v.y, v.y, fmaf(v.z, v.z, v.w * v.w)));
#pragma unroll
        for (int off = 32; off > 0; off >>= 1) s += __shfl_xor(s, off);
        if (lane == 0) sq[row] = s;
        ssum += s;  // butterfly left full sum in every lane
    }
    float4 cp; cp.x = c0; cp.y = c1; cp.z = c2; cp.w = c3;
    *(float4*)&cpart[wave][lane * 4] = cp;
    if (lane == 0) spart[wave] = ssum;
    __syncthreads();
    const float cs = cpart[0][t] + cpart[1][t] + cpart[2][t] + cpart[3][t];
    const int rep = blockIdx.x & 7;  // 8 replicas -> 64 adds/address
    atomicAdd(&colsum_r[rep * 256 + t], cs);  // poison -3e-13/rep: harmless
    if (t == 0) atomicAdd(&Ssum_r[rep], spart[0] + spart[1] + spart[2] + spart[3]);
}

// ---------------- k_bw: one block computes exp2 scale c2 once ----------------
// Same summation order as the old per-block prologue -> bit-identical c2.
__global__ __launch_bounds__(256) void k_bw(const float* __restrict__ colsum_r,
                                            const float* __restrict__ Ssum_r,
                                            float* __restrict__ c2out) {
    __shared__ double sred[4];
    const int t = threadIdx.x, lane = t & 63, wave = t >> 6;
    float csf = 0.f;
#pragma unroll
    for (int r = 0; r < 8; ++r) csf += colsum_r[r * 256 + t];
    double p = (double)csf * (double)csf;
#pragma unroll
    for (int off = 32; off > 0; off >>= 1) p += __shfl_xor(p, off);
    if (lane == 0) sred[wave] = p;
    __syncthreads();
    if (t == 0) {
        const double SS = sred[0] + sred[1] + sred[2] + sred[3];
        float Sf = 0.f;
#pragma unroll
        for (int r = 0; r < 8; ++r) Sf += Ssum_r[r];
        const double sum_d2 = 2.0 * (double)M_TOT * (double)Sf - 2.0 * SS;
        const double bw = sum_d2 / ((double)M_TOT * (double)M_TOT - (double)M_TOT);
        c2out[0] = (float)(1.4426950408889634 / (4.0 * bw));  // exp2 scale
    }
}

// ---------------- k_gram: barrier-free direct-global Gram, 4 blocks/CU -------
// 1040 blocks x 256 threads x 2 tiles; no LDS in the K-loop, no barriers;
// 4 waves/SIMD provide the latency cover (TLP, not ILP). Compiler schedules
// loads just-in-time within the 128-VGPR budget.
__global__ __launch_bounds__(256, 4) void k_gram(const float* __restrict__ sq,
                                                 const float* __restrict__ c2p,
                                                 double* __restrict__ acc,
                                                 unsigned* __restrict__ cnt,
                                                 float* __restrict__ out) {
    __shared__ double redw[4][3];

    // XCD-band swizzle (1040 = 8*130): same-XCD blocks contiguous in triangle.
    const int bid = (int)blockIdx.x;
    const int cc = (bid & 7) * 130 + (bid >> 3);
    const int f0 = cc * 2;  // first flat tile index of this block (2 tiles)

    const int t = threadIdx.x;
    const int lane = t & 63, wave = t >> 6;
    const int l15 = lane & 15, quad = lane >> 4;
    const int wrow = (wave >> 1) * 64, wcol = (wave & 1) * 64;
    const int a0 = (wave >> 1) * 4, b0 = (wave & 1) * 4;  // frag chunk bases
    const int laneoff = quad * 128 + l15 * 8;  // elems; = lane*16B in a chunk

    const float c2 = c2p[0];  // wave-uniform scalar load
    const float twoc2 = 2.f * c2;

    // triangular decode of f0 -> (ti, tj), tj >= ti
    int ti = (int)((129.0f - sqrtf(16641.0f - 8.0f * (float)f0)) * 0.5f);
    if (ti < 0) ti = 0; if (ti > NT - 1) ti = NT - 1;
    while (ti * NT - ti * (ti - 1) / 2 > f0) --ti;
    while ((ti + 1) * NT - (ti + 1) * ti / 2 <= f0) ++ti;
    int tj = ti + (f0 - (ti * NT - ti * (ti - 1) / 2));

    // per-wave frag base pointers (include chunk base + laneoff)
    const ushort_t* cA = g_zf + (size_t)(ti * 8 + a0) * 4096 + laneoff;
    const ushort_t* cB = g_zf + (size_t)(tj * 8 + b0) * 4096 + laneoff;

    double lxx = 0.0, lxy = 0.0, lyy = 0.0;

#pragma unroll 1
    for (int s = 0; s < 2; ++s) {
        floatx4 accv[4][4];
#pragma unroll
        for (int mi = 0; mi < 4; ++mi)
#pragma unroll
            for (int ni = 0; ni < 4; ++ni) accv[mi][ni] = (floatx4)0.f;

        // plain per-slice load+MFMA; unrolled so the compiler hoists loads
        // ahead to its register limit (no barriers -> free reordering).
#pragma unroll
        for (int kk = 0; kk < 8; ++kk) {
            short8 af[4], bf[4];
#pragma unroll
            for (int mi = 0; mi < 4; ++mi)
                af[mi] = *(const short8*)(cA + (size_t)mi * 4096 + kk * 512);
#pragma unroll
            for (int ni = 0; ni < 4; ++ni)
                bf[ni] = *(const short8*)(cB + (size_t)ni * 4096 + kk * 512);
#pragma unroll
            for (int mi = 0; mi < 4; ++mi)
#pragma unroll
                for (int ni = 0; ni < 4; ++ni)
                    accv[mi][ni] = __builtin_amdgcn_mfma_f32_16x16x32_bf16(
                        af[mi], bf[ni], accv[mi][ni], 0, 0, 0);
        }

        // ---- epilogue for (ti, tj). C/D: col = lane&15, row = quad*4+reg.
        const int arow0 = ti * TILE, brow0 = tj * TILE;
        float nsj[4];
#pragma unroll
        for (int ni = 0; ni < 4; ++ni)
            nsj[ni] = -c2 * sq[brow0 + wcol + ni * 16 + l15];
        floatx4 nsi4[4];
#pragma unroll
        for (int mi = 0; mi < 4; ++mi) {
            const float4 sv = *(const float4*)&sq[arow0 + wrow + mi * 16 + quad * 4];
            nsi4[mi][0] = -c2 * sv.x; nsi4[mi][1] = -c2 * sv.y;
            nsi4[mi][2] = -c2 * sv.z; nsi4[mi][3] = -c2 * sv.w;
        }
        floatx4 sum4 = (floatx4)0.f;
#pragma unroll
        for (int mi = 0; mi < 4; ++mi) {
#pragma unroll
            for (int ni = 0; ni < 4; ++ni) {
                const floatx4 addv = nsi4[mi] + (floatx4)nsj[ni];
                floatx4 arg = twoc2 * accv[mi][ni] + addv;
                floatx4 tt;
#pragma unroll
                for (int r = 0; r < 4; ++r) tt[r] = exp2f(fminf(arg[r], 0.f));
                const floatx4 t2 = tt * tt, t4 = t2 * t2, t8 = t4 * t4, t16 = t8 * t8;
                sum4 += (tt + t2) + (t4 + t8) + t16;
            }
        }
        const float fsum = (sum4[0] + sum4[1]) + (sum4[2] + sum4[3]);
        const double contrib = ((ti == tj) ? 1.0 : 2.0) * (double)fsum;
        if (tj < NT_HALF)       lxx += contrib;   // block-uniform branches
        else if (ti < NT_HALF)  lxy += contrib;
        else                    lyy += contrib;

        // advance compute tile
        ++tj; if (tj == NT) { ++ti; tj = ti; }
        cA = g_zf + (size_t)(ti * 8 + a0) * 4096 + laneoff;
        cB = g_zf + (size_t)(tj * 8 + b0) * 4096 + laneoff;
    }

    // ---- block reduction + finalize ----
#pragma unroll
    for (int off = 32; off > 0; off >>= 1) {
        lxx += __shfl_xor(lxx, off);
        lxy += __shfl_xor(lxy, off);
        lyy += __shfl_xor(lyy, off);
    }
    if (lane == 0) { redw[wave][0] = lxx; redw[wave][1] = lxy; redw[wave][2] = lyy; }
    __syncthreads();
    if (t == 0) {
        double sxx = 0.0, sxy = 0.0, syy = 0.0;
#pragma unroll
        for (int wv = 0; wv < 4; ++wv) {
            sxx += redw[wv][0]; sxy += redw[wv][1]; syy += redw[wv][2];
        }
        if (sxx != 0.0) atomicAdd(&acc[0], sxx);
        if (sxy != 0.0) atomicAdd(&acc[1], sxy);
        if (syy != 0.0) atomicAdd(&acc[2], syy);
        __threadfence();  // release region adds before counter bump
        const unsigned old = atomicAdd(cnt, 1u);
        // counter starts at 0xAAAAAAAA (ws poison) or 0 — accept either
        if (old == (0xAAAAAAAAu + (unsigned)(NCHUNK - 1)) ||
            old == (unsigned)(NCHUNK - 1)) {
            const double xx = atomicAdd(&acc[0], 0.0);  // coherent reads
            const double xy = atomicAdd(&acc[1], 0.0);
            const double yy = atomicAdd(&acc[2], 0.0);
            out[0] = (float)((xx + yy - xy) *
                             (1.0 / ((double)N_HALF * (double)N_HALF)));
        }
    }
}

extern "C" void kernel_launch(void* const* d_in, const int* in_sizes, int n_in,
                              void* d_out, int out_size, void* d_ws, size_t ws_size,
                              hipStream_t stream) {
    const float* X = (const float*)d_in[0];
    const float* Y = (const float*)d_in[1];
    char* ws = (char*)d_ws;
    float* sq        = (float*)ws;               // 8192 f32  [0, 32768)
    float* colsum_r  = (float*)(ws + 32768);     // 8*256 f32 [32768, 40960)
    float* Ssum_r    = (float*)(ws + 40960);     // 8 f32     [40960, 40992)
    unsigned* cnt    = (unsigned*)(ws + 40992);  // 1 u32
    double* acc      = (double*)(ws + 41000);    // 3 f64 (8-aligned)
    float* c2ws      = (float*)(ws + 41024);     // 1 f32
    float* out = (float*)d_out;

    hipLaunchKernelGGL(k_prep, dim3(512), dim3(256), 0, stream,
                       X, Y, sq, colsum_r, Ssum_r);
    hipLaunchKernelGGL(k_bw, dim3(1), dim3(256), 0, stream,
                       colsum_r, Ssum_r, c2ws);
    hipLaunchKernelGGL(k_gram, dim3(NCHUNK), dim3(256), 0, stream,
                       sq, c2ws, acc, cnt, out);
}

// Round 11
// 131.262 us; speedup vs baseline: 1.1169x; 1.1169x over previous
//
#include <hip/hip_runtime.h>
#include <math.h>

// MMD loss. Z = concat(X,Y) [8192 x 256] fp32.
// Round 19: R18 canary fired (VGPR=64, WRITE 35MB: allocator spilled acc
//   chasing 8 waves/SIMD). 2 waves/SIMD is the legal max with 64-reg acc +
//   frags; R13 (counted-vmcnt 1-slice ring, 48.5us) is the proven best.
//   Two deltas on R13, no new structure:
//   (a) 2 kk-slices per ring buffer (4x16KB, 66KB LDS, 2 blocks/CU): 4
//       phases/tile instead of 8 -> half the vmcnt/barrier fixed cost, 32
//       MFMA cover/phase. Steady vmcnt(16) (2 bufs in flight), tail 8/0;
//       stage at phase g writes buf (g+3)&3 consumed at g-1 (same proof).
//   (b) k_bw launch deleted: last k_prep block (atomic counter, poison-base
//       tolerant) computes c2 with identical summation order via coherent
//       atomic reads -> bit-identical c2; 3 launches -> 2.
// Math (R5-R18 verified, absmax 0.0): 1-phase bf16 Gram, sq exact fp32;
//   d2 = sq_i + sq_j - 2 z_i.z_j; bandwidth analytic
//   (sum d2 = 2M*S - 2||sum z||^2); K = t+t^2+t^4+t^8+t^16, t=exp(-d2/(4bw));
//   out = (Sxx + Syy - Sxy_both)/n^2, fp64 accumulation.

#define N_HALF 4096
#define DIM 256
#define M_TOT 8192
#define TILE 128
#define NT 64
#define NT_HALF 32
#define NCHUNK 512   // blocks; 480 do 4 tiles, 32 (cc%16==0) do 5: 2080 total
#define NPREP 512    // k_prep blocks

typedef unsigned short ushort_t;
typedef __attribute__((ext_vector_type(8))) short short8;   // 8 bf16 = 4 VGPRs
typedef __attribute__((ext_vector_type(4))) float floatx4;  // MFMA C/D

// Fragment-swizzled bf16 Z (4 MB). For row-block rb (16 rows) and k-chunk kk
// (32 k): g_zf[rb*4096 + kk*512 + q*128 + m*8 + j] = Z[rb*16+m][kk*32+q*8+j].
// The 16B unit of lane (quad=q, l15=m) sits at byte lane*16 within the 1KB
// chunk: MFMA frag ds_read_b128 is linear in lane -> conflict-free; staging
// global_load_lds (dest base+lane*16, src +lane*16) is a pure linear copy.
__device__ ushort_t g_zf[M_TOT * DIM];

__device__ __forceinline__ ushort_t f2bf(float f) {  // RNE, finite inputs
    unsigned u = __float_as_uint(f);
    u += 0x7fffu + ((u >> 16) & 1u);
    return (ushort_t)(u >> 16);
}

__device__ __forceinline__ void gload_lds16(const ushort_t* g, ushort_t* l) {
    __builtin_amdgcn_global_load_lds(
        (const __attribute__((address_space(1))) void*)g,
        (__attribute__((address_space(3))) void*)l, 16, 0, 0);
}

// Stage two consecutive kk-slices (A 8KB + B 8KB) into one 16KB ring buffer.
// Buffer layout (ushorts): A slice s chunk c at s*4096 + c*512;
//                          B slice s chunk c at 8192 + s*4096 + c*512.
// Wave w stages chunks {2w, 2w+1}: 8 gload_lds of 1KB per wave.
__device__ __forceinline__ void stage2(const ushort_t* gA, const ushort_t* gB,
                                       int kk0, ushort_t* buf, int wave, int lane) {
#pragma unroll
    for (int s = 0; s < 2; ++s) {
#pragma unroll
        for (int i = 0; i < 2; ++i) {
            const int c = wave * 2 + i;
            gload_lds16(gA + (size_t)c * 4096 + (kk0 + s) * 512 + lane * 8,
                        buf + s * 4096 + c * 512);
            gload_lds16(gB + (size_t)c * 4096 + (kk0 + s) * 512 + lane * 8,
                        buf + 8192 + s * 4096 + c * 512);
        }
    }
}

// ---------------- k_prep: convert + norms + col sums + inline bandwidth ------
// 512 blocks x 256 threads; wave w owns 4 rows; lane l owns cols [4l,4l+4).
// Last block to finish (atomic counter) computes c2 (old k_bw body,
// identical summation order, coherent atomic reads) -> one less launch.
__global__ __launch_bounds__(256) void k_prep(const float* __restrict__ X,
                                              const float* __restrict__ Y,
                                              float* __restrict__ sq,
                                              float* __restrict__ colsum_r,
                                              float* __restrict__ Ssum_r,
                                              unsigned* __restrict__ pcnt,
                                              float* __restrict__ c2out) {
    __shared__ float cpart[4][256];
    __shared__ float spart[4];
    __shared__ double sred[4];
    __shared__ int lastflag;
    const int t = threadIdx.x, wave = t >> 6, lane = t & 63;
    const int row0 = blockIdx.x * 16 + wave * 4;
    // swizzle coords for this lane's 4 columns [4l, 4l+4)
    const int kk = lane >> 3, q = (lane >> 1) & 3, j0 = (lane & 1) * 4;
    float c0 = 0.f, c1 = 0.f, c2 = 0.f, c3 = 0.f, ssum = 0.f;
#pragma unroll
    for (int i = 0; i < 4; ++i) {
        const int row = row0 + i;
        const float* p = (row < N_HALF) ? (X + (size_t)row * DIM)
                                        : (Y + (size_t)(row - N_HALF) * DIM);
        const float4 v = *((const float4*)p + lane);
        ushort4 hi;
        hi.x = f2bf(v.x); hi.y = f2bf(v.y); hi.z = f2bf(v.z); hi.w = f2bf(v.w);
        const int rb = row >> 4, m = row & 15;
        *(ushort4*)(g_zf + (size_t)rb * 4096 + kk * 512 + q * 128 + m * 8 + j0) = hi;
        c0 += v.x; c1 += v.y; c2 += v.z; c3 += v.w;
        float s = fmaf(v.x, v.x, fmaf(v.y, v.y, fmaf(v.z, v.z, v.w * v.w)));
#pragma unroll
        for (int off = 32; off > 0; off >>= 1) s += __shfl_xor(s, off);
        if (lane == 0) sq[row] = s;
        ssum += s;  // butterfly left full sum in every lane
    }
    float4 cp; cp.x = c0; cp.y = c1; cp.z = c2; cp.w = c3;
    *(float4*)&cpart[wave][lane * 4] = cp;
    if (lane == 0) spart[wave] = ssum;
    __syncthreads();
    const float cs = cpart[0][t] + cpart[1][t] + cpart[2][t] + cpart[3][t];
    const int rep = blockIdx.x & 7;  // 8 replicas -> 64 adds/address
    atomicAdd(&colsum_r[rep * 256 + t], cs);  // poison -3e-13/rep: harmless
    if (t == 0) atomicAdd(&Ssum_r[rep], spart[0] + spart[1] + spart[2] + spart[3]);

    // ---- last-block bandwidth finalize (replaces k_bw kernel) ----
    if (t == 0) {
        __threadfence();  // release this block's adds before counter bump
        const unsigned old = atomicAdd(pcnt, 1u);
        // counter starts at 0xAAAAAAAA (ws poison) or 0 — accept either
        lastflag = (old == (0xAAAAAAAAu + (unsigned)(NPREP - 1)) ||
                    old == (unsigned)(NPREP - 1)) ? 1 : 0;
    }
    __syncthreads();
    if (lastflag) {
        // identical summation order to the old k_bw -> bit-identical c2;
        // atomicAdd(.,0) reads are coherent at device scope.
        float csf = 0.f;
#pragma unroll
        for (int r = 0; r < 8; ++r) csf += atomicAdd(&colsum_r[r * 256 + t], 0.f);
        double p = (double)csf * (double)csf;
#pragma unroll
        for (int off = 32; off > 0; off >>= 1) p += __shfl_xor(p, off);
        if (lane == 0) sred[wave] = p;
        __syncthreads();
        if (t == 0) {
            const double SS = sred[0] + sred[1] + sred[2] + sred[3];
            float Sf = 0.f;
#pragma unroll
            for (int r = 0; r < 8; ++r) Sf += atomicAdd(&Ssum_r[r], 0.f);
            const double sum_d2 = 2.0 * (double)M_TOT * (double)Sf - 2.0 * SS;
            const double bw =
                sum_d2 / ((double)M_TOT * (double)M_TOT - (double)M_TOT);
            c2out[0] = (float)(1.4426950408889634 / (4.0 * bw));  // exp2 scale
        }
        // kernel end flushes; k_gram (next launch) sees c2out.
    }
}

// ---------------- k_gram: counted-vmcnt 2-slice-ring MFMA Gram ---------------
// 512 blocks x 256 threads = 2 blocks/CU; 4x16KB LDS ring (2 slices each),
// 4 phases/tile; steady vmcnt(16) keeps 2 buffers in flight across barriers.
__global__ __launch_bounds__(256, 2) void k_gram(const float* __restrict__ sq,
                                                 const float* __restrict__ c2p,
                                                 double* __restrict__ acc,
                                                 unsigned* __restrict__ cnt,
                                                 float* __restrict__ out) {
    __shared__ __attribute__((aligned(16))) ushort_t lds[4][16384];
    __shared__ double redw[4][3];

    // XCD-band swizzle (512 = 8*64): same-XCD blocks contiguous in triangle.
    const int bid = (int)blockIdx.x;
    const int cc = (bid & 7) * 64 + (bid >> 3);
    // 32 long blocks (cc%16==0 -> 4 per XCD) do 5 tiles; rest do 4.
    const int nst = ((cc & 15) == 0) ? 5 : 4;
    const int f0 = cc * 4 + ((cc + 15) >> 4);  // first flat tile of this block

    const int t = threadIdx.x;
    const int lane = t & 63, wave = t >> 6;
    const int l15 = lane & 15, quad = lane >> 4;
    const int wrow = (wave >> 1) * 64, wcol = (wave & 1) * 64;
    const int a0 = (wave >> 1) * 4, b0 = (wave & 1) * 4;  // frag chunk bases
    const int laneoff = quad * 128 + l15 * 8;  // = lane*16B: linear, no conflict

    const float c2 = c2p[0];  // wave-uniform scalar load
    const float twoc2 = 2.f * c2;

    // triangular decode of f0 -> (ti, tj), tj >= ti
    int ti = (int)((129.0f - sqrtf(16641.0f - 8.0f * (float)f0)) * 0.5f);
    if (ti < 0) ti = 0; if (ti > NT - 1) ti = NT - 1;
    while (ti * NT - ti * (ti - 1) / 2 > f0) --ti;
    while ((ti + 1) * NT - (ti + 1) * ti / 2 <= f0) ++ti;
    int tj = ti + (f0 - (ti * NT - ti * (ti - 1) / 2));

    // stage stream in double-slice units (4 per tile; runs 3 bufs ahead)
    int s_ti = ti, s_tj = tj, s_k2 = 0;
    const ushort_t* sgA = g_zf + (size_t)s_ti * 32768;
    const ushort_t* sgB = g_zf + (size_t)s_tj * 32768;
#define ADV_STAGE() do { if (++s_k2 == 4) { s_k2 = 0; ++s_tj;                 \
        if (s_tj == NT) { ++s_ti; s_tj = s_ti; }                              \
        sgA = g_zf + (size_t)s_ti * 32768;                                    \
        sgB = g_zf + (size_t)s_tj * 32768; } } while (0)

    // prime buffers 0,1,2 (= slices 0..5): 24 loads in flight per wave
#pragma unroll
    for (int p = 0; p < 3; ++p) {
        stage2(sgA, sgB, s_k2 * 2, lds[p], wave, lane);
        ADV_STAGE();
    }

    double lxx = 0.0, lxy = 0.0, lyy = 0.0;

#pragma unroll 1
    for (int s = 0; s < nst; ++s) {
        const bool last = (s == nst - 1);

        floatx4 accv[4][4];
#pragma unroll
        for (int mi = 0; mi < 4; ++mi)
#pragma unroll
            for (int ni = 0; ni < 4; ++ni) accv[mi][ni] = (floatx4)0.f;

#pragma unroll
        for (int kk2 = 0; kk2 < 4; ++kk2) {
            // counted wait: buffer about to be read (8 loads) retired once
            // <=16 outstanding (in-order retire; 2 newer buffers = 16 loads).
            // Tail of last tile: 8 then 0. Epilogue sq loads only make these
            // waits conservative (extra entries ahead in the queue).
            if (last && kk2 == 2)      asm volatile("s_waitcnt vmcnt(8)" ::: "memory");
            else if (last && kk2 == 3) asm volatile("s_waitcnt vmcnt(0)" ::: "memory");
            else                       asm volatile("s_waitcnt vmcnt(16)" ::: "memory");
            __builtin_amdgcn_s_barrier();
            __builtin_amdgcn_sched_barrier(0);

            const ushort_t* buf = lds[kk2];  // phase g=4s+kk2 -> buf g&3 = kk2

            // issue stage of buffer g+3 into buf (kk2+3)&3 (consumed at phase
            // g-1; all waves passed this phase's barrier after reading it)
            if (!last || kk2 == 0) {
                stage2(sgA, sgB, s_k2 * 2, lds[(kk2 + 3) & 3], wave, lane);
                ADV_STAGE();
            }

            // compute both slices of this buffer (ds_read + 16 MFMA each)
#pragma unroll
            for (int sl = 0; sl < 2; ++sl) {
                const ushort_t* lA = buf + sl * 4096;
                const ushort_t* lB = buf + 8192 + sl * 4096;
                short8 af[4], bf[4];
#pragma unroll
                for (int mi = 0; mi < 4; ++mi)
                    af[mi] = *(const short8*)(lA + (a0 + mi) * 512 + laneoff);
#pragma unroll
                for (int ni = 0; ni < 4; ++ni)
                    bf[ni] = *(const short8*)(lB + (b0 + ni) * 512 + laneoff);
                __builtin_amdgcn_s_setprio(1);
#pragma unroll
                for (int mi = 0; mi < 4; ++mi)
#pragma unroll
                    for (int ni = 0; ni < 4; ++ni)
                        accv[mi][ni] = __builtin_amdgcn_mfma_f32_16x16x32_bf16(
                            af[mi], bf[ni], accv[mi][ni], 0, 0, 0);
                __builtin_amdgcn_s_setprio(0);
            }
        }

        // ---- epilogue for (ti, tj). C/D: col = lane&15, row = quad*4+reg.
        const int arow0 = ti * TILE, brow0 = tj * TILE;
        float nsj[4];
#pragma unroll
        for (int ni = 0; ni < 4; ++ni)
            nsj[ni] = -c2 * sq[brow0 + wcol + ni * 16 + l15];
        floatx4 nsi4[4];
#pragma unroll
        for (int mi = 0; mi < 4; ++mi) {
            const float4 sv = *(const float4*)&sq[arow0 + wrow + mi * 16 + quad * 4];
            nsi4[mi][0] = -c2 * sv.x; nsi4[mi][1] = -c2 * sv.y;
            nsi4[mi][2] = -c2 * sv.z; nsi4[mi][3] = -c2 * sv.w;
        }
        floatx4 sum4 = (floatx4)0.f;
#pragma unroll
        for (int mi = 0; mi < 4; ++mi) {
#pragma unroll
            for (int ni = 0; ni < 4; ++ni) {
                const floatx4 addv = nsi4[mi] + (floatx4)nsj[ni];
                floatx4 arg = twoc2 * accv[mi][ni] + addv;
                floatx4 tt;
#pragma unroll
                for (int r = 0; r < 4; ++r) tt[r] = exp2f(fminf(arg[r], 0.f));
                const floatx4 t2 = tt * tt, t4 = t2 * t2, t8 = t4 * t4, t16 = t8 * t8;
                sum4 += (tt + t2) + (t4 + t8) + t16;
            }
        }
        const float fsum = (sum4[0] + sum4[1]) + (sum4[2] + sum4[3]);
        const double contrib = ((ti == tj) ? 1.0 : 2.0) * (double)fsum;
        if (tj < NT_HALF)       lxx += contrib;   // block-uniform branches
        else if (ti < NT_HALF)  lxy += contrib;
        else                    lyy += contrib;

        // advance compute tile
        ++tj; if (tj == NT) { ++ti; tj = ti; }
    }
#undef ADV_STAGE

    // ---- block reduction + finalize ----
#pragma unroll
    for (int off = 32; off > 0; off >>= 1) {
        lxx += __shfl_xor(lxx, off);
        lxy += __shfl_xor(lxy, off);
        lyy += __shfl_xor(lyy, off);
    }
    if (lane == 0) { redw[wave][0] = lxx; redw[wave][1] = lxy; redw[wave][2] = lyy; }
    __syncthreads();
    if (t == 0) {
        double sxx = 0.0, sxy = 0.0, syy = 0.0;
#pragma unroll
        for (int wv = 0; wv < 4; ++wv) {
            sxx += redw[wv][0]; sxy += redw[wv][1]; syy += redw[wv][2];
        }
        if (sxx != 0.0) atomicAdd(&acc[0], sxx);
        if (sxy != 0.0) atomicAdd(&acc[1], sxy);
        if (syy != 0.0) atomicAdd(&acc[2], syy);
        __threadfence();  // release region adds before counter bump
        const unsigned old = atomicAdd(cnt, 1u);
        // counter starts at 0xAAAAAAAA (ws poison) or 0 — accept either
        if (old == (0xAAAAAAAAu + (unsigned)(NCHUNK - 1)) ||
            old == (unsigned)(NCHUNK - 1)) {
            const double xx = atomicAdd(&acc[0], 0.0);  // coherent reads
            const double xy = atomicAdd(&acc[1], 0.0);
            const double yy = atomicAdd(&acc[2], 0.0);
            out[0] = (float)((xx + yy - xy) *
                             (1.0 / ((double)N_HALF * (double)N_HALF)));
        }
    }
}

extern "C" void kernel_launch(void* const* d_in, const int* in_sizes, int n_in,
                              void* d_out, int out_size, void* d_ws, size_t ws_size,
                              hipStream_t stream) {
    const float* X = (const float*)d_in[0];
    const float* Y = (const float*)d_in[1];
    char* ws = (char*)d_ws;
    float* sq        = (float*)ws;               // 8192 f32  [0, 32768)
    float* colsum_r  = (float*)(ws + 32768);     // 8*256 f32 [32768, 40960)
    float* Ssum_r    = (float*)(ws + 40960);     // 8 f32     [40960, 40992)
    unsigned* cnt    = (unsigned*)(ws + 40992);  // 1 u32 (k_gram finalize)
    double* acc      = (double*)(ws + 41000);    // 3 f64 (8-aligned)
    float* c2ws      = (float*)(ws + 41024);     // 1 f32
    unsigned* pcnt   = (unsigned*)(ws + 41028);  // 1 u32 (k_prep finalize)
    float* out = (float*)d_out;

    hipLaunchKernelGGL(k_prep, dim3(NPREP), dim3(256), 0, stream,
                       X, Y, sq, colsum_r, Ssum_r, pcnt, c2ws);
    hipLaunchKernelGGL(k_gram, dim3(NCHUNK), dim3(256), 0, stream,
                       sq, c2ws, acc, cnt, out);
}